// Round 10
// baseline (490.443 us; speedup 1.0000x reference)
//
#include <hip/hip_runtime.h>
#include <stdint.h>

#define NG 256
#define HW (512*512)
#define NCELL 1024          // 32x32 cells
#define CAP 384             // bucket capacity per cell (Poisson(256), max ~330)
#define SPILL_CAP 4096
#define NBIN 256            // bin blocks
#define PXB (HW/NBIN)       // 1024 pixels per bin-block
#define TWO_PI_F 6.283185307179586f
#define L2E 1.4426950408889634f
#define INV2PI_D 0.15915494309189535

static __device__ __forceinline__ float clampf(float x, float lo, float hi) {
    return fminf(fmaxf(x, lo), hi);
}

// ---------- per-gabor constants (f64 -> correctly-rounded f32) ----------
static __device__ __forceinline__ void compute_consts(
    int n,
    const float* __restrict__ u, const float* __restrict__ v,
    const float* __restrict__ theta, const float* __restrict__ rel_sigma,
    const float* __restrict__ rel_freq, const float* __restrict__ gamma,
    const float* __restrict__ psi, const float* __restrict__ amplitude,
    float4& A, float4& B, float4& C, float4& D)
{
    const float uc = clampf(u[n], -1.f, 1.f);
    const float vc = clampf(v[n], -1.f, 1.f);
    const float th = clampf(theta[n], -2.f, 2.f) * TWO_PI_F;
    const float sg = clampf(rel_sigma[n], 1e-5f, 5.f);
    const float gm = clampf(gamma[n], 1e-5f, 5.f);
    const float cr = (float)::cos((double)th);
    const float sr = (float)::sin((double)th);
    const float i2s = 1.0f / (2.0f * sg * sg);
    const float i2g = 1.0f / (2.0f * gm * gm);
    const float E  = (float)::exp((double)rel_freq[n]);
    const float fq = TWO_PI_F / E;          // f32 division, mirrors np
    A = make_float4(uc, vc, cr, sr);
    B = make_float4(-(i2s * L2E), -(i2g * L2E), fq, 0.f);  // ready for exp2
    float ac[3], as[3];
    #pragma unroll
    for (int c = 0; c < 3; ++c) {
        const float ph = clampf(psi[n*3 + c], -1.f, 1.f) * TWO_PI_F;
        const float a  = clampf(amplitude[n*3 + c], 0.f, 1.f);
        ac[c] = a * (float)::cos((double)ph);
        as[c] = a * (float)::sin((double)ph);
    }
    C = make_float4(ac[0], ac[1], ac[2], 0.f);
    D = make_float4(as[0], as[1], as[2], 0.f);
}

// ---------- 1-pixel accumulate (spill + fallback paths) ----------
static __device__ __forceinline__ void accum_list(
    const float4* __restrict__ base, int ngab,
    float gx, float gy, float& a0, float& a1, float& a2)
{
    const float c1f = 0.15915494309189535f;
    const float c2f = (float)(INV2PI_D - (double)0.15915494309189535f);
    for (int j = 0; j < ngab; ++j) {
        const float4 k0 = base[j];
        const float4 k1 = base[NG + j];
        const float dx = gx - k0.x;
        const float dy = gy - k0.y;
        float xr, yr;
        {
            #pragma clang fp contract(off)
            xr = dx * k0.z + dy * k0.w;
            yr = dy * k0.z - dx * k0.w;
        }
        const float e2 = fmaf(yr * yr, k1.y, xr * xr * k1.x);
        if (e2 > -20.0f) {
            const float g = __builtin_amdgcn_exp2f(e2);
            float fx;
            {
                #pragma clang fp contract(off)
                fx = k1.z * xr;
            }
            const float nn = __builtin_rintf(fx * c1f);
            float t = __builtin_fmaf(fx, c1f, -nn);
            t = __builtin_fmaf(fx, c2f, t);
            const float s = __builtin_amdgcn_sinf(t);
            const float c = __builtin_amdgcn_cosf(t);
            const float4 k2 = base[2*NG + j];
            const float4 k3 = base[3*NG + j];
            const float gc = g * c, gs = g * s;
            a0 = fmaf(gc, k2.x, fmaf(-gs, k3.x, a0));
            a1 = fmaf(gc, k2.y, fmaf(-gs, k3.y, a1));
            a2 = fmaf(gc, k2.z, fmaf(-gs, k3.z, a2));
        }
    }
}

// ---------- kernel A: binning (blocks 0..255) + consts (block 256) ----------
__global__ __launch_bounds__(256) void gabor_bin_consts(
    const float* __restrict__ grid_x, const float* __restrict__ grid_y,
    const float* __restrict__ u, const float* __restrict__ v,
    const float* __restrict__ theta, const float* __restrict__ rel_sigma,
    const float* __restrict__ rel_freq, const float* __restrict__ gamma,
    const float* __restrict__ psi, const float* __restrict__ amplitude,
    float4* __restrict__ consts, int* __restrict__ counts,
    float4* __restrict__ bpx,
    int* __restrict__ spill, int* __restrict__ spilln)
{
    const int tid = threadIdx.x;
    if (blockIdx.x == NBIN) {  // consts block, runs concurrently with binning
        float4 A, B, C, D;
        compute_consts(tid, u, v, theta, rel_sigma, rel_freq, gamma, psi,
                       amplitude, A, B, C, D);
        consts[tid] = A; consts[NG+tid] = B;
        consts[2*NG+tid] = C; consts[3*NG+tid] = D;
        return;
    }
    __shared__ int hist[NCELL];
    __shared__ int base[NCELL];
    #pragma unroll
    for (int i = 0; i < NCELL/256; ++i) hist[i*256 + tid] = 0;
    __syncthreads();

    uint32_t rec[PXB/256];
    float px[PXB/256], py[PXB/256];
    const int p0 = blockIdx.x * PXB;
    #pragma unroll
    for (int i = 0; i < PXB/256; ++i) {
        const int p = p0 + i*256 + tid;
        const float x = grid_x[p], y = grid_y[p];
        px[i] = x; py[i] = y;
        int ix = (int)(x * 32.0f); ix = min(max(ix, 0), 31);
        int iy = (int)(y * 32.0f); iy = min(max(iy, 0), 31);
        const int cell = iy*32 + ix;
        const int lr = atomicAdd(&hist[cell], 1);       // LDS atomic: cheap
        rec[i] = ((uint32_t)cell << 11) | (uint32_t)lr; // lr < 1024 fits 11b
    }
    __syncthreads();
    #pragma unroll
    for (int i = 0; i < NCELL/256; ++i) {
        const int c = i*256 + tid;
        const int h = hist[c];
        base[c] = (h > 0) ? atomicAdd(&counts[c], h) : 0;  // 1024 addresses
    }
    __syncthreads();
    #pragma unroll
    for (int i = 0; i < PXB/256; ++i) {
        const int p = p0 + i*256 + tid;
        const int cell = (int)(rec[i] >> 11);
        const int g = base[cell] + (int)(rec[i] & 0x7FFu);
        if (g < CAP) {
            bpx[cell*CAP + g] =
                make_float4(__int_as_float(p), px[i], py[i], 0.f);
        } else {
            const int t2 = atomicAdd(spilln, 1);
            if (t2 < SPILL_CAP) spill[t2] = p;
        }
    }
}

// ---------- kernel B: render. 2 blocks/cell, each half the gabor list for
// ---------- ALL the cell's pixels -> 8 blocks/CU (2x TLP). Partials go to
// ---------- bpart; the LAST block to finish (device-scope ticket) combines.
__global__ __launch_bounds__(256, 8) void gabor_render(
    const float4* __restrict__ consts, const int* __restrict__ counts,
    const float4* __restrict__ bpx, float4* __restrict__ bpart,
    int* __restrict__ done,
    const int* __restrict__ spill, const int* __restrict__ spilln,
    const float* __restrict__ grid_x, const float* __restrict__ grid_y,
    float* __restrict__ out)
{
    __shared__ float4 cs[4 * NG];
    __shared__ int s_wb1[4], s_wb2[4];
    __shared__ int s_who;
    const int cell = blockIdx.x >> 1, half = blockIdx.x & 1;
    const int tid = threadIdx.x;
    const float cxc = ((cell & 31) + 0.5f) * 0.03125f;
    const float cyc = ((cell >> 5) + 0.5f) * 0.03125f;

    // --- inline cull + G1/G2 segmented compaction (identical in both blocks) ---
    {
        const float4 A = consts[tid];
        const float4 B = consts[NG + tid];
        const float4 C = consts[2*NG + tid];
        const float4 D = consts[3*NG + tid];
        const float dx = cxc - A.x, dy = cyc - A.y;
        const float xrc = dx * A.z + dy * A.w;
        const float yrc = dy * A.z - dx * A.w;
        const float R = 0.0222f;            // cell half-diagonal + slack
        const float axr = fabsf(xrc), ayr = fabsf(yrc);
        const float xl = fmaxf(axr - R, 0.f), yl = fmaxf(ayr - R, 0.f);
        const float xh = axr + R,            yh = ayr + R;
        // B.x,B.y <= 0: e2 over the cell lies in [e2min, e2max]
        const float e2max = xl*xl*B.x + yl*yl*B.y;
        const float e2min = xh*xh*B.x + yh*yh*B.y;
        const bool nz = (C.x != 0.f) | (C.y != 0.f) | (C.z != 0.f) |
                        (D.x != 0.f) | (D.y != 0.f) | (D.z != 0.f);
        const bool act = (e2max > -20.0f) && nz;
        const bool g1  = act && (e2min > -20.0f);   // hits EVERY px in cell
        const bool g2  = act && !g1;                // edge gabor
        const unsigned long long m1 = __ballot(g1);
        const unsigned long long m2 = __ballot(g2);
        const int lane = tid & 63, w = tid >> 6;
        if (lane == 0) { s_wb1[w] = __popcll(m1); s_wb2[w] = __popcll(m2); }
        __syncthreads();
        const int n1t = s_wb1[0] + s_wb1[1] + s_wb1[2] + s_wb1[3];
        int b1 = 0, b2 = n1t;
        #pragma unroll
        for (int i = 0; i < 4; ++i) {
            b1 += (i < w) ? s_wb1[i] : 0;
            b2 += (i < w) ? s_wb2[i] : 0;
        }
        const unsigned long long lm = (1ull << lane) - 1ull;
        if (g1) {
            const int pos = b1 + __popcll(m1 & lm);
            cs[pos] = A; cs[NG+pos] = B; cs[2*NG+pos] = C; cs[3*NG+pos] = D;
        }
        if (g2) {
            const int pos = b2 + __popcll(m2 & lm);
            cs[pos] = A; cs[NG+pos] = B; cs[2*NG+pos] = C; cs[3*NG+pos] = D;
        }
        __syncthreads();
    }
    const int n1 = s_wb1[0] + s_wb1[1] + s_wb1[2] + s_wb1[3];
    const int n2 = s_wb2[0] + s_wb2[1] + s_wb2[2] + s_wb2[3];
    // this block's sub-ranges: half of G1, half of G2
    const int g1a = half ? (n1 >> 1) : 0;
    const int g1b = half ? n1        : (n1 >> 1);
    const int g2a = n1 + (half ? (n2 >> 1) : 0);
    const int g2b = n1 + (half ? n2        : (n2 >> 1));

    // --- pixel loop: partial sums over this block's gabor halves ---
    const float c1f = 0.15915494309189535f;
    const float c2f = (float)(INV2PI_D - (double)0.15915494309189535f);
    const int cnt = min(counts[cell], CAP);
    const int sb = cell * CAP;
    float4* myp = bpart + (size_t)(cell*2 + half) * CAP;
    for (int i = tid; i < cnt; i += 256) {
        const float4 pxk = bpx[sb + i];
        const float gx = pxk.y, gy = pxk.z;
        float a0 = 0.f, a1 = 0.f, a2 = 0.f;
        // G1 sub-range: branchless
        #pragma unroll 2
        for (int j = g1a; j < g1b; ++j) {
            const float4 k0 = cs[j];
            const float4 k1 = cs[NG + j];
            const float dx = gx - k0.x;
            const float dy = gy - k0.y;
            float xr, yr;
            {
                // phase-critical: match np's separately-rounded mul/add
                #pragma clang fp contract(off)
                xr = dx * k0.z + dy * k0.w;
                yr = dy * k0.z - dx * k0.w;
            }
            const float e2 = fmaf(yr * yr, k1.y, xr * xr * k1.x);
            const float g = __builtin_amdgcn_exp2f(e2);
            float fx;
            {
                #pragma clang fp contract(off)
                fx = k1.z * xr;              // phase-critical rounding
            }
            const float nn = __builtin_rintf(fx * c1f);
            float t = __builtin_fmaf(fx, c1f, -nn);
            t = __builtin_fmaf(fx, c2f, t);
            const float s = __builtin_amdgcn_sinf(t);
            const float c = __builtin_amdgcn_cosf(t);
            const float4 k2 = cs[2*NG + j];
            const float4 k3 = cs[3*NG + j];
            const float gc = g * c, gs = g * s;
            a0 = fmaf(gc, k2.x, fmaf(-gs, k3.x, a0));
            a1 = fmaf(gc, k2.y, fmaf(-gs, k3.y, a1));
            a2 = fmaf(gc, k2.z, fmaf(-gs, k3.z, a2));
        }
        // G2 sub-range: edge gabors, keep the skip branch
        for (int j = g2a; j < g2b; ++j) {
            const float4 k0 = cs[j];
            const float4 k1 = cs[NG + j];
            const float dx = gx - k0.x;
            const float dy = gy - k0.y;
            float xr, yr;
            {
                #pragma clang fp contract(off)
                xr = dx * k0.z + dy * k0.w;
                yr = dy * k0.z - dx * k0.w;
            }
            const float e2 = fmaf(yr * yr, k1.y, xr * xr * k1.x);
            if (e2 > -20.0f) {
                const float g = __builtin_amdgcn_exp2f(e2);
                float fx;
                {
                    #pragma clang fp contract(off)
                    fx = k1.z * xr;
                }
                const float nn = __builtin_rintf(fx * c1f);
                float t = __builtin_fmaf(fx, c1f, -nn);
                t = __builtin_fmaf(fx, c2f, t);
                const float s = __builtin_amdgcn_sinf(t);
                const float c = __builtin_amdgcn_cosf(t);
                const float4 k2 = cs[2*NG + j];
                const float4 k3 = cs[3*NG + j];
                const float gc = g * c, gs = g * s;
                a0 = fmaf(gc, k2.x, fmaf(-gs, k3.x, a0));
                a1 = fmaf(gc, k2.y, fmaf(-gs, k3.y, a1));
                a2 = fmaf(gc, k2.z, fmaf(-gs, k3.z, a2));
            }
        }
        myp[i] = make_float4(a0, a1, a2, 0.f);
    }

    // --- ticket: last block for this cell combines partial[0]+partial[1] ---
    __syncthreads();
    __threadfence();                         // release partial writes
    if (tid == 0) s_who = atomicAdd(&done[cell], 1);
    __syncthreads();
    if (s_who == 1) {
        __threadfence();                     // acquire other block's writes
        const float4* q0 = bpart + (size_t)(cell*2)     * CAP;
        const float4* q1 = bpart + (size_t)(cell*2 + 1) * CAP;
        for (int i = tid; i < cnt; i += 256) {
            const float4 a = q0[i];
            const float4 b = q1[i];
            const int p = __float_as_int(bpx[sb + i].x);
            out[p]        = clampf(a.x + b.x, -1.f, 1.f);
            out[HW + p]   = clampf(a.y + b.y, -1.f, 1.f);
            out[2*HW + p] = clampf(a.z + b.z, -1.f, 1.f);
        }
    }

    // spill pixels (normally zero): block for cell 0, half 0, full list
    if (blockIdx.x == 0) {
        const int sc = min(*spilln, SPILL_CAP);
        for (int i = tid; i < sc; i += 256) {
            const int p = spill[i];
            const float gx = grid_x[p], gy = grid_y[p];
            float a0 = 0.f, a1 = 0.f, a2 = 0.f;
            accum_list(consts, NG, gx, gy, a0, a1, a2);
            out[p]        = clampf(a0, -1.f, 1.f);
            out[HW + p]   = clampf(a1, -1.f, 1.f);
            out[2*HW + p] = clampf(a2, -1.f, 1.f);
        }
    }
}

// ---------- fallback paths (ws too small) ----------
__global__ __launch_bounds__(256) void gabor_consts_kernel(
    const float* __restrict__ u, const float* __restrict__ v,
    const float* __restrict__ theta, const float* __restrict__ rel_sigma,
    const float* __restrict__ rel_freq, const float* __restrict__ gamma,
    const float* __restrict__ psi, const float* __restrict__ amplitude,
    float4* __restrict__ ws)
{
    const int n = threadIdx.x;
    float4 A, B, C, D;
    compute_consts(n, u, v, theta, rel_sigma, rel_freq, gamma, psi, amplitude,
                   A, B, C, D);
    ws[n] = A; ws[NG + n] = B; ws[2*NG + n] = C; ws[3*NG + n] = D;
}

__global__ __launch_bounds__(256) void gabor_fwd_ws(
    const float4* __restrict__ ws,
    const float* __restrict__ grid_x, const float* __restrict__ grid_y,
    float* __restrict__ out)
{
    __shared__ float4 cs[4 * NG];
    const int tid = threadIdx.x;
    cs[tid]        = ws[tid];
    cs[tid + NG]   = ws[tid + NG];
    cs[tid + 2*NG] = ws[tid + 2*NG];
    cs[tid + 3*NG] = ws[tid + 3*NG];
    __syncthreads();
    const int p = blockIdx.x * 256 + tid;
    const float gx = grid_x[p], gy = grid_y[p];
    float a0 = 0.f, a1 = 0.f, a2 = 0.f;
    accum_list(cs, NG, gx, gy, a0, a1, a2);
    out[p]        = clampf(a0, -1.f, 1.f);
    out[HW + p]   = clampf(a1, -1.f, 1.f);
    out[2*HW + p] = clampf(a2, -1.f, 1.f);
}

__global__ __launch_bounds__(256) void gabor_fwd_fused(
    const float* __restrict__ grid_x, const float* __restrict__ grid_y,
    const float* __restrict__ u, const float* __restrict__ v,
    const float* __restrict__ theta, const float* __restrict__ rel_sigma,
    const float* __restrict__ rel_freq, const float* __restrict__ gamma,
    const float* __restrict__ psi, const float* __restrict__ amplitude,
    float* __restrict__ out)
{
    __shared__ float4 cs[4 * NG];
    const int tid = threadIdx.x;
    {
        float4 A, B, C, D;
        compute_consts(tid, u, v, theta, rel_sigma, rel_freq, gamma, psi,
                       amplitude, A, B, C, D);
        cs[tid] = A; cs[tid + NG] = B; cs[tid + 2*NG] = C; cs[tid + 3*NG] = D;
    }
    __syncthreads();
    const int p = blockIdx.x * 256 + tid;
    const float gx = grid_x[p], gy = grid_y[p];
    float a0 = 0.f, a1 = 0.f, a2 = 0.f;
    accum_list(cs, NG, gx, gy, a0, a1, a2);
    out[p]        = clampf(a0, -1.f, 1.f);
    out[HW + p]   = clampf(a1, -1.f, 1.f);
    out[2*HW + p] = clampf(a2, -1.f, 1.f);
}

extern "C" void kernel_launch(void* const* d_in, const int* in_sizes, int n_in,
                              void* d_out, int out_size, void* d_ws, size_t ws_size,
                              hipStream_t stream) {
    const float* grid_x    = (const float*)d_in[0];
    const float* grid_y    = (const float*)d_in[1];
    const float* u         = (const float*)d_in[2];
    const float* v         = (const float*)d_in[3];
    const float* theta     = (const float*)d_in[4];
    const float* rel_sigma = (const float*)d_in[5];
    const float* rel_freq  = (const float*)d_in[6];
    const float* gamma     = (const float*)d_in[7];
    const float* psi       = (const float*)d_in[8];
    const float* amplitude = (const float*)d_in[9];
    float* out = (float*)d_out;

    // ws layout (256B-aligned)
    const size_t OFF_CONSTS = 0;            // 16384
    const size_t OFF_COUNTS = 16384;        // 4096
    const size_t OFF_SPN    = 20480;        // 256
    const size_t OFF_DONE   = 20736;        // 4096
    const size_t OFF_SPILL  = 24832;        // 16384
    const size_t OFF_BPX    = 41216;        // 1024*384*16 = 6291456
    const size_t OFF_BPART  = 6332672;      // 2*1024*384*16 = 12582912
    const size_t NEED       = 18915584;

    char* w = (char*)d_ws;

    if (ws_size >= NEED) {
        float4* consts = (float4*)(w + OFF_CONSTS);
        int*    counts = (int*)(w + OFF_COUNTS);
        int*    spn    = (int*)(w + OFF_SPN);
        int*    done   = (int*)(w + OFF_DONE);
        int*    spill  = (int*)(w + OFF_SPILL);
        float4* bpx    = (float4*)(w + OFF_BPX);
        float4* bpart  = (float4*)(w + OFF_BPART);

        // zero counts + spilln + done (graph-capturable memset node)
        hipMemsetAsync(w + OFF_COUNTS, 0, 4096 + 256 + 4096, stream);
        gabor_bin_consts<<<NBIN + 1, 256, 0, stream>>>(
            grid_x, grid_y, u, v, theta, rel_sigma, rel_freq, gamma,
            psi, amplitude, consts, counts, bpx, spill, spn);
        gabor_render<<<2*NCELL, 256, 0, stream>>>(
            consts, counts, bpx, bpart, done, spill, spn, grid_x, grid_y, out);
    } else if (ws_size >= 4u * NG * sizeof(float4)) {
        float4* ws = (float4*)d_ws;
        gabor_consts_kernel<<<1, NG, 0, stream>>>(
            u, v, theta, rel_sigma, rel_freq, gamma, psi, amplitude, ws);
        gabor_fwd_ws<<<HW / 256, 256, 0, stream>>>(ws, grid_x, grid_y, out);
    } else {
        gabor_fwd_fused<<<HW / 256, 256, 0, stream>>>(
            grid_x, grid_y, u, v, theta, rel_sigma, rel_freq, gamma,
            psi, amplitude, out);
    }
}

// Round 11
// 44.258 us; speedup vs baseline: 11.0814x; 11.0814x over previous
//
#include <hip/hip_runtime.h>
#include <stdint.h>

#define NG 256
#define HW (512*512)
#define NCELL 1024          // 32x32 cells
#define CAP 384             // bucket capacity per cell (Poisson(256), max ~330)
#define SPILL_CAP 4096
#define NBIN 256            // bin blocks
#define PXB (HW/NBIN)       // 1024 pixels per bin-block
#define TWO_PI_F 6.283185307179586f
#define L2E 1.4426950408889634f
#define INV2PI_D 0.15915494309189535

static __device__ __forceinline__ float clampf(float x, float lo, float hi) {
    return fminf(fmaxf(x, lo), hi);
}

// ---------- per-gabor constants (f64 -> correctly-rounded f32) ----------
static __device__ __forceinline__ void compute_consts(
    int n,
    const float* __restrict__ u, const float* __restrict__ v,
    const float* __restrict__ theta, const float* __restrict__ rel_sigma,
    const float* __restrict__ rel_freq, const float* __restrict__ gamma,
    const float* __restrict__ psi, const float* __restrict__ amplitude,
    float4& A, float4& B, float4& C, float4& D)
{
    const float uc = clampf(u[n], -1.f, 1.f);
    const float vc = clampf(v[n], -1.f, 1.f);
    const float th = clampf(theta[n], -2.f, 2.f) * TWO_PI_F;
    const float sg = clampf(rel_sigma[n], 1e-5f, 5.f);
    const float gm = clampf(gamma[n], 1e-5f, 5.f);
    const float cr = (float)::cos((double)th);
    const float sr = (float)::sin((double)th);
    const float i2s = 1.0f / (2.0f * sg * sg);
    const float i2g = 1.0f / (2.0f * gm * gm);
    const float E  = (float)::exp((double)rel_freq[n]);
    const float fq = TWO_PI_F / E;          // f32 division, mirrors np
    A = make_float4(uc, vc, cr, sr);
    B = make_float4(-(i2s * L2E), -(i2g * L2E), fq, 0.f);  // ready for exp2
    float ac[3], as[3];
    #pragma unroll
    for (int c = 0; c < 3; ++c) {
        const float ph = clampf(psi[n*3 + c], -1.f, 1.f) * TWO_PI_F;
        const float a  = clampf(amplitude[n*3 + c], 0.f, 1.f);
        ac[c] = a * (float)::cos((double)ph);
        as[c] = a * (float)::sin((double)ph);
    }
    C = make_float4(ac[0], ac[1], ac[2], 0.f);
    D = make_float4(as[0], as[1], as[2], 0.f);
}

// ---------- 1-pixel accumulate (spill + fallback paths) ----------
static __device__ __forceinline__ void accum_list(
    const float4* __restrict__ base, int ngab,
    float gx, float gy, float& a0, float& a1, float& a2)
{
    const float c1f = 0.15915494309189535f;
    const float c2f = (float)(INV2PI_D - (double)0.15915494309189535f);
    for (int j = 0; j < ngab; ++j) {
        const float4 k0 = base[j];
        const float4 k1 = base[NG + j];
        const float dx = gx - k0.x;
        const float dy = gy - k0.y;
        float xr, yr;
        {
            #pragma clang fp contract(off)
            xr = dx * k0.z + dy * k0.w;
            yr = dy * k0.z - dx * k0.w;
        }
        const float e2 = fmaf(yr * yr, k1.y, xr * xr * k1.x);
        if (e2 > -20.0f) {
            const float g = __builtin_amdgcn_exp2f(e2);
            float fx;
            {
                #pragma clang fp contract(off)
                fx = k1.z * xr;
            }
            const float nn = __builtin_rintf(fx * c1f);
            float t = __builtin_fmaf(fx, c1f, -nn);
            t = __builtin_fmaf(fx, c2f, t);
            const float s = __builtin_amdgcn_sinf(t);
            const float c = __builtin_amdgcn_cosf(t);
            const float4 k2 = base[2*NG + j];
            const float4 k3 = base[3*NG + j];
            const float gc = g * c, gs = g * s;
            a0 = fmaf(gc, k2.x, fmaf(-gs, k3.x, a0));
            a1 = fmaf(gc, k2.y, fmaf(-gs, k3.y, a1));
            a2 = fmaf(gc, k2.z, fmaf(-gs, k3.z, a2));
        }
    }
}

// ---------- kernel A: binning (blocks 0..255) + consts (block 256) ----------
__global__ __launch_bounds__(256) void gabor_bin_consts(
    const float* __restrict__ grid_x, const float* __restrict__ grid_y,
    const float* __restrict__ u, const float* __restrict__ v,
    const float* __restrict__ theta, const float* __restrict__ rel_sigma,
    const float* __restrict__ rel_freq, const float* __restrict__ gamma,
    const float* __restrict__ psi, const float* __restrict__ amplitude,
    float4* __restrict__ consts, int* __restrict__ counts,
    float4* __restrict__ bpx,
    int* __restrict__ spill, int* __restrict__ spilln)
{
    const int tid = threadIdx.x;
    if (blockIdx.x == NBIN) {  // consts block, runs concurrently with binning
        float4 A, B, C, D;
        compute_consts(tid, u, v, theta, rel_sigma, rel_freq, gamma, psi,
                       amplitude, A, B, C, D);
        consts[tid] = A; consts[NG+tid] = B;
        consts[2*NG+tid] = C; consts[3*NG+tid] = D;
        return;
    }
    __shared__ int hist[NCELL];
    __shared__ int base[NCELL];
    #pragma unroll
    for (int i = 0; i < NCELL/256; ++i) hist[i*256 + tid] = 0;
    __syncthreads();

    uint32_t rec[PXB/256];
    float px[PXB/256], py[PXB/256];
    const int p0 = blockIdx.x * PXB;
    #pragma unroll
    for (int i = 0; i < PXB/256; ++i) {
        const int p = p0 + i*256 + tid;
        const float x = grid_x[p], y = grid_y[p];
        px[i] = x; py[i] = y;
        int ix = (int)(x * 32.0f); ix = min(max(ix, 0), 31);
        int iy = (int)(y * 32.0f); iy = min(max(iy, 0), 31);
        const int cell = iy*32 + ix;
        const int lr = atomicAdd(&hist[cell], 1);       // LDS atomic: cheap
        rec[i] = ((uint32_t)cell << 11) | (uint32_t)lr; // lr < 1024 fits 11b
    }
    __syncthreads();
    #pragma unroll
    for (int i = 0; i < NCELL/256; ++i) {
        const int c = i*256 + tid;
        const int h = hist[c];
        base[c] = (h > 0) ? atomicAdd(&counts[c], h) : 0;  // 1024 addresses
    }
    __syncthreads();
    #pragma unroll
    for (int i = 0; i < PXB/256; ++i) {
        const int p = p0 + i*256 + tid;
        const int cell = (int)(rec[i] >> 11);
        const int g = base[cell] + (int)(rec[i] & 0x7FFu);
        if (g < CAP) {
            bpx[cell*CAP + g] =
                make_float4(__int_as_float(p), px[i], py[i], 0.f);
        } else {
            const int t2 = atomicAdd(spilln, 1);
            if (t2 < SPILL_CAP) spill[t2] = p;
        }
    }
}

// ---------- kernel B: render partials. 2 blocks/cell, each half the gabor
// ---------- list for ALL the cell's pixels -> 8 blocks/CU (2x TLP).
// ---------- NO fences/atomics: ordering comes from the kernel boundary.
__global__ __launch_bounds__(256, 8) void gabor_render(
    const float4* __restrict__ consts, const int* __restrict__ counts,
    const float4* __restrict__ bpx, float4* __restrict__ bpart)
{
    __shared__ float4 cs[4 * NG];
    __shared__ int s_wb1[4], s_wb2[4];
    const int cell = blockIdx.x >> 1, half = blockIdx.x & 1;
    const int tid = threadIdx.x;
    const float cxc = ((cell & 31) + 0.5f) * 0.03125f;
    const float cyc = ((cell >> 5) + 0.5f) * 0.03125f;

    // --- inline cull + G1/G2 segmented compaction (identical in both blocks) ---
    {
        const float4 A = consts[tid];
        const float4 B = consts[NG + tid];
        const float4 C = consts[2*NG + tid];
        const float4 D = consts[3*NG + tid];
        const float dx = cxc - A.x, dy = cyc - A.y;
        const float xrc = dx * A.z + dy * A.w;
        const float yrc = dy * A.z - dx * A.w;
        const float R = 0.0222f;            // cell half-diagonal + slack
        const float axr = fabsf(xrc), ayr = fabsf(yrc);
        const float xl = fmaxf(axr - R, 0.f), yl = fmaxf(ayr - R, 0.f);
        const float xh = axr + R,            yh = ayr + R;
        // B.x,B.y <= 0: e2 over the cell lies in [e2min, e2max]
        const float e2max = xl*xl*B.x + yl*yl*B.y;
        const float e2min = xh*xh*B.x + yh*yh*B.y;
        const bool nz = (C.x != 0.f) | (C.y != 0.f) | (C.z != 0.f) |
                        (D.x != 0.f) | (D.y != 0.f) | (D.z != 0.f);
        const bool act = (e2max > -20.0f) && nz;
        const bool g1  = act && (e2min > -20.0f);   // hits EVERY px in cell
        const bool g2  = act && !g1;                // edge gabor
        const unsigned long long m1 = __ballot(g1);
        const unsigned long long m2 = __ballot(g2);
        const int lane = tid & 63, w = tid >> 6;
        if (lane == 0) { s_wb1[w] = __popcll(m1); s_wb2[w] = __popcll(m2); }
        __syncthreads();
        const int n1t = s_wb1[0] + s_wb1[1] + s_wb1[2] + s_wb1[3];
        int b1 = 0, b2 = n1t;
        #pragma unroll
        for (int i = 0; i < 4; ++i) {
            b1 += (i < w) ? s_wb1[i] : 0;
            b2 += (i < w) ? s_wb2[i] : 0;
        }
        const unsigned long long lm = (1ull << lane) - 1ull;
        if (g1) {
            const int pos = b1 + __popcll(m1 & lm);
            cs[pos] = A; cs[NG+pos] = B; cs[2*NG+pos] = C; cs[3*NG+pos] = D;
        }
        if (g2) {
            const int pos = b2 + __popcll(m2 & lm);
            cs[pos] = A; cs[NG+pos] = B; cs[2*NG+pos] = C; cs[3*NG+pos] = D;
        }
        __syncthreads();
    }
    const int n1 = s_wb1[0] + s_wb1[1] + s_wb1[2] + s_wb1[3];
    const int n2 = s_wb2[0] + s_wb2[1] + s_wb2[2] + s_wb2[3];
    // this block's sub-ranges: half of G1, half of G2
    const int g1a = half ? (n1 >> 1) : 0;
    const int g1b = half ? n1        : (n1 >> 1);
    const int g2a = n1 + (half ? (n2 >> 1) : 0);
    const int g2b = n1 + (half ? n2        : (n2 >> 1));

    // --- pixel loop: partial sums over this block's gabor halves ---
    const float c1f = 0.15915494309189535f;
    const float c2f = (float)(INV2PI_D - (double)0.15915494309189535f);
    const int cnt = min(counts[cell], CAP);
    const int sb = cell * CAP;
    float4* myp = bpart + (size_t)(cell*2 + half) * CAP;
    for (int i = tid; i < cnt; i += 256) {
        const float4 pxk = bpx[sb + i];
        const float gx = pxk.y, gy = pxk.z;
        float a0 = 0.f, a1 = 0.f, a2 = 0.f;
        // G1 sub-range: branchless
        #pragma unroll 2
        for (int j = g1a; j < g1b; ++j) {
            const float4 k0 = cs[j];
            const float4 k1 = cs[NG + j];
            const float dx = gx - k0.x;
            const float dy = gy - k0.y;
            float xr, yr;
            {
                // phase-critical: match np's separately-rounded mul/add
                #pragma clang fp contract(off)
                xr = dx * k0.z + dy * k0.w;
                yr = dy * k0.z - dx * k0.w;
            }
            const float e2 = fmaf(yr * yr, k1.y, xr * xr * k1.x);
            const float g = __builtin_amdgcn_exp2f(e2);
            float fx;
            {
                #pragma clang fp contract(off)
                fx = k1.z * xr;              // phase-critical rounding
            }
            const float nn = __builtin_rintf(fx * c1f);
            float t = __builtin_fmaf(fx, c1f, -nn);
            t = __builtin_fmaf(fx, c2f, t);
            const float s = __builtin_amdgcn_sinf(t);
            const float c = __builtin_amdgcn_cosf(t);
            const float4 k2 = cs[2*NG + j];
            const float4 k3 = cs[3*NG + j];
            const float gc = g * c, gs = g * s;
            a0 = fmaf(gc, k2.x, fmaf(-gs, k3.x, a0));
            a1 = fmaf(gc, k2.y, fmaf(-gs, k3.y, a1));
            a2 = fmaf(gc, k2.z, fmaf(-gs, k3.z, a2));
        }
        // G2 sub-range: edge gabors, keep the skip branch
        for (int j = g2a; j < g2b; ++j) {
            const float4 k0 = cs[j];
            const float4 k1 = cs[NG + j];
            const float dx = gx - k0.x;
            const float dy = gy - k0.y;
            float xr, yr;
            {
                #pragma clang fp contract(off)
                xr = dx * k0.z + dy * k0.w;
                yr = dy * k0.z - dx * k0.w;
            }
            const float e2 = fmaf(yr * yr, k1.y, xr * xr * k1.x);
            if (e2 > -20.0f) {
                const float g = __builtin_amdgcn_exp2f(e2);
                float fx;
                {
                    #pragma clang fp contract(off)
                    fx = k1.z * xr;
                }
                const float nn = __builtin_rintf(fx * c1f);
                float t = __builtin_fmaf(fx, c1f, -nn);
                t = __builtin_fmaf(fx, c2f, t);
                const float s = __builtin_amdgcn_sinf(t);
                const float c = __builtin_amdgcn_cosf(t);
                const float4 k2 = cs[2*NG + j];
                const float4 k3 = cs[3*NG + j];
                const float gc = g * c, gs = g * s;
                a0 = fmaf(gc, k2.x, fmaf(-gs, k3.x, a0));
                a1 = fmaf(gc, k2.y, fmaf(-gs, k3.y, a1));
                a2 = fmaf(gc, k2.z, fmaf(-gs, k3.z, a2));
            }
        }
        myp[i] = make_float4(a0, a1, a2, 0.f);
    }
}

// ---------- kernel C: combine partials, clamp, write out (+ spill) ----------
__global__ __launch_bounds__(256) void gabor_combine(
    const float4* __restrict__ consts, const int* __restrict__ counts,
    const float4* __restrict__ bpx, const float4* __restrict__ bpart,
    const int* __restrict__ spill, const int* __restrict__ spilln,
    const float* __restrict__ grid_x, const float* __restrict__ grid_y,
    float* __restrict__ out)
{
    const int cell = blockIdx.x;
    const int tid = threadIdx.x;
    const int cnt = min(counts[cell], CAP);
    const int sb = cell * CAP;
    const float4* q0 = bpart + (size_t)(cell*2)     * CAP;
    const float4* q1 = bpart + (size_t)(cell*2 + 1) * CAP;
    for (int i = tid; i < cnt; i += 256) {
        const float4 a = q0[i];
        const float4 b = q1[i];
        const int p = __float_as_int(bpx[sb + i].x);
        out[p]        = clampf(a.x + b.x, -1.f, 1.f);
        out[HW + p]   = clampf(a.y + b.y, -1.f, 1.f);
        out[2*HW + p] = clampf(a.z + b.z, -1.f, 1.f);
    }
    if (cell == 0) {    // spill pixels (normally zero) with full gabor list
        const int sc = min(*spilln, SPILL_CAP);
        for (int i = tid; i < sc; i += 256) {
            const int p = spill[i];
            const float gx = grid_x[p], gy = grid_y[p];
            float a0 = 0.f, a1 = 0.f, a2 = 0.f;
            accum_list(consts, NG, gx, gy, a0, a1, a2);
            out[p]        = clampf(a0, -1.f, 1.f);
            out[HW + p]   = clampf(a1, -1.f, 1.f);
            out[2*HW + p] = clampf(a2, -1.f, 1.f);
        }
    }
}

// ---------- fallback paths (ws too small) ----------
__global__ __launch_bounds__(256) void gabor_consts_kernel(
    const float* __restrict__ u, const float* __restrict__ v,
    const float* __restrict__ theta, const float* __restrict__ rel_sigma,
    const float* __restrict__ rel_freq, const float* __restrict__ gamma,
    const float* __restrict__ psi, const float* __restrict__ amplitude,
    float4* __restrict__ ws)
{
    const int n = threadIdx.x;
    float4 A, B, C, D;
    compute_consts(n, u, v, theta, rel_sigma, rel_freq, gamma, psi, amplitude,
                   A, B, C, D);
    ws[n] = A; ws[NG + n] = B; ws[2*NG + n] = C; ws[3*NG + n] = D;
}

__global__ __launch_bounds__(256) void gabor_fwd_ws(
    const float4* __restrict__ ws,
    const float* __restrict__ grid_x, const float* __restrict__ grid_y,
    float* __restrict__ out)
{
    __shared__ float4 cs[4 * NG];
    const int tid = threadIdx.x;
    cs[tid]        = ws[tid];
    cs[tid + NG]   = ws[tid + NG];
    cs[tid + 2*NG] = ws[tid + 2*NG];
    cs[tid + 3*NG] = ws[tid + 3*NG];
    __syncthreads();
    const int p = blockIdx.x * 256 + tid;
    const float gx = grid_x[p], gy = grid_y[p];
    float a0 = 0.f, a1 = 0.f, a2 = 0.f;
    accum_list(cs, NG, gx, gy, a0, a1, a2);
    out[p]        = clampf(a0, -1.f, 1.f);
    out[HW + p]   = clampf(a1, -1.f, 1.f);
    out[2*HW + p] = clampf(a2, -1.f, 1.f);
}

__global__ __launch_bounds__(256) void gabor_fwd_fused(
    const float* __restrict__ grid_x, const float* __restrict__ grid_y,
    const float* __restrict__ u, const float* __restrict__ v,
    const float* __restrict__ theta, const float* __restrict__ rel_sigma,
    const float* __restrict__ rel_freq, const float* __restrict__ gamma,
    const float* __restrict__ psi, const float* __restrict__ amplitude,
    float* __restrict__ out)
{
    __shared__ float4 cs[4 * NG];
    const int tid = threadIdx.x;
    {
        float4 A, B, C, D;
        compute_consts(tid, u, v, theta, rel_sigma, rel_freq, gamma, psi,
                       amplitude, A, B, C, D);
        cs[tid] = A; cs[tid + NG] = B; cs[tid + 2*NG] = C; cs[tid + 3*NG] = D;
    }
    __syncthreads();
    const int p = blockIdx.x * 256 + tid;
    const float gx = grid_x[p], gy = grid_y[p];
    float a0 = 0.f, a1 = 0.f, a2 = 0.f;
    accum_list(cs, NG, gx, gy, a0, a1, a2);
    out[p]        = clampf(a0, -1.f, 1.f);
    out[HW + p]   = clampf(a1, -1.f, 1.f);
    out[2*HW + p] = clampf(a2, -1.f, 1.f);
}

extern "C" void kernel_launch(void* const* d_in, const int* in_sizes, int n_in,
                              void* d_out, int out_size, void* d_ws, size_t ws_size,
                              hipStream_t stream) {
    const float* grid_x    = (const float*)d_in[0];
    const float* grid_y    = (const float*)d_in[1];
    const float* u         = (const float*)d_in[2];
    const float* v         = (const float*)d_in[3];
    const float* theta     = (const float*)d_in[4];
    const float* rel_sigma = (const float*)d_in[5];
    const float* rel_freq  = (const float*)d_in[6];
    const float* gamma     = (const float*)d_in[7];
    const float* psi       = (const float*)d_in[8];
    const float* amplitude = (const float*)d_in[9];
    float* out = (float*)d_out;

    // ws layout (256B-aligned)
    const size_t OFF_CONSTS = 0;            // 16384
    const size_t OFF_COUNTS = 16384;        // 4096
    const size_t OFF_SPN    = 20480;        // 256
    const size_t OFF_SPILL  = 24832;        // 16384
    const size_t OFF_BPX    = 41216;        // 1024*384*16 = 6291456
    const size_t OFF_BPART  = 6332672;      // 2*1024*384*16 = 12582912
    const size_t NEED       = 18915584;

    char* w = (char*)d_ws;

    if (ws_size >= NEED) {
        float4* consts = (float4*)(w + OFF_CONSTS);
        int*    counts = (int*)(w + OFF_COUNTS);
        int*    spn    = (int*)(w + OFF_SPN);
        int*    spill  = (int*)(w + OFF_SPILL);
        float4* bpx    = (float4*)(w + OFF_BPX);
        float4* bpart  = (float4*)(w + OFF_BPART);

        // zero counts + spilln (graph-capturable memset node)
        hipMemsetAsync(w + OFF_COUNTS, 0, 4096 + 256, stream);
        gabor_bin_consts<<<NBIN + 1, 256, 0, stream>>>(
            grid_x, grid_y, u, v, theta, rel_sigma, rel_freq, gamma,
            psi, amplitude, consts, counts, bpx, spill, spn);
        gabor_render<<<2*NCELL, 256, 0, stream>>>(consts, counts, bpx, bpart);
        gabor_combine<<<NCELL, 256, 0, stream>>>(
            consts, counts, bpx, bpart, spill, spn, grid_x, grid_y, out);
    } else if (ws_size >= 4u * NG * sizeof(float4)) {
        float4* ws = (float4*)d_ws;
        gabor_consts_kernel<<<1, NG, 0, stream>>>(
            u, v, theta, rel_sigma, rel_freq, gamma, psi, amplitude, ws);
        gabor_fwd_ws<<<HW / 256, 256, 0, stream>>>(ws, grid_x, grid_y, out);
    } else {
        gabor_fwd_fused<<<HW / 256, 256, 0, stream>>>(
            grid_x, grid_y, u, v, theta, rel_sigma, rel_freq, gamma,
            psi, amplitude, out);
    }
}

// Round 12
// 33.712 us; speedup vs baseline: 14.5479x; 1.3128x over previous
//
#include <hip/hip_runtime.h>
#include <stdint.h>

#define NG 256
#define HW (512*512)
#define NCELL 1024          // 32x32 cells
#define CAP 384             // bucket capacity per cell (Poisson(256), max ~330)
#define SPILL_CAP 4096
#define NBIN 256            // bin blocks
#define PXB (HW/NBIN)       // 1024 pixels per bin-block
#define TWO_PI_F 6.283185307179586f
#define L2E 1.4426950408889634f
#define INV2PI_D 0.15915494309189535

typedef float v2f __attribute__((ext_vector_type(2)));

static __device__ __forceinline__ float clampf(float x, float lo, float hi) {
    return fminf(fmaxf(x, lo), hi);
}

// ---------- per-gabor constants (f64 -> correctly-rounded f32) ----------
static __device__ __forceinline__ void compute_consts(
    int n,
    const float* __restrict__ u, const float* __restrict__ v,
    const float* __restrict__ theta, const float* __restrict__ rel_sigma,
    const float* __restrict__ rel_freq, const float* __restrict__ gamma,
    const float* __restrict__ psi, const float* __restrict__ amplitude,
    float4& A, float4& B, float4& C, float4& D)
{
    const float uc = clampf(u[n], -1.f, 1.f);
    const float vc = clampf(v[n], -1.f, 1.f);
    const float th = clampf(theta[n], -2.f, 2.f) * TWO_PI_F;
    const float sg = clampf(rel_sigma[n], 1e-5f, 5.f);
    const float gm = clampf(gamma[n], 1e-5f, 5.f);
    const float cr = (float)::cos((double)th);
    const float sr = (float)::sin((double)th);
    const float i2s = 1.0f / (2.0f * sg * sg);
    const float i2g = 1.0f / (2.0f * gm * gm);
    const float E  = (float)::exp((double)rel_freq[n]);
    const float fq = TWO_PI_F / E;          // f32 division, mirrors np
    A = make_float4(uc, vc, cr, sr);
    B = make_float4(-(i2s * L2E), -(i2g * L2E), fq, 0.f);  // ready for exp2
    float ac[3], as[3];
    #pragma unroll
    for (int c = 0; c < 3; ++c) {
        const float ph = clampf(psi[n*3 + c], -1.f, 1.f) * TWO_PI_F;
        const float a  = clampf(amplitude[n*3 + c], 0.f, 1.f);
        ac[c] = a * (float)::cos((double)ph);
        as[c] = a * (float)::sin((double)ph);
    }
    C = make_float4(ac[0], ac[1], ac[2], 0.f);
    D = make_float4(as[0], as[1], as[2], 0.f);
}

// ---------- 1-pixel accumulate (spill + fallback paths) ----------
static __device__ __forceinline__ void accum_list(
    const float4* __restrict__ base, int ngab,
    float gx, float gy, float& a0, float& a1, float& a2)
{
    const float c1f = 0.15915494309189535f;
    const float c2f = (float)(INV2PI_D - (double)0.15915494309189535f);
    for (int j = 0; j < ngab; ++j) {
        const float4 k0 = base[j];
        const float4 k1 = base[NG + j];
        const float dx = gx - k0.x;
        const float dy = gy - k0.y;
        float xr, yr;
        {
            #pragma clang fp contract(off)
            xr = dx * k0.z + dy * k0.w;
            yr = dy * k0.z - dx * k0.w;
        }
        const float e2 = fmaf(yr * yr, k1.y, xr * xr * k1.x);
        if (e2 > -20.0f) {
            const float g = __builtin_amdgcn_exp2f(e2);
            float fx;
            {
                #pragma clang fp contract(off)
                fx = k1.z * xr;
            }
            const float nn = __builtin_rintf(fx * c1f);
            float t = __builtin_fmaf(fx, c1f, -nn);
            t = __builtin_fmaf(fx, c2f, t);
            const float s = __builtin_amdgcn_sinf(t);
            const float c = __builtin_amdgcn_cosf(t);
            const float4 k2 = base[2*NG + j];
            const float4 k3 = base[3*NG + j];
            const float gc = g * c, gs = g * s;
            a0 = fmaf(gc, k2.x, fmaf(-gs, k3.x, a0));
            a1 = fmaf(gc, k2.y, fmaf(-gs, k3.y, a1));
            a2 = fmaf(gc, k2.z, fmaf(-gs, k3.z, a2));
        }
    }
}

// ---------- kernel A: binning (blocks 0..255) + consts (block 256) ----------
__global__ __launch_bounds__(256) void gabor_bin_consts(
    const float* __restrict__ grid_x, const float* __restrict__ grid_y,
    const float* __restrict__ u, const float* __restrict__ v,
    const float* __restrict__ theta, const float* __restrict__ rel_sigma,
    const float* __restrict__ rel_freq, const float* __restrict__ gamma,
    const float* __restrict__ psi, const float* __restrict__ amplitude,
    float4* __restrict__ consts, int* __restrict__ counts,
    float4* __restrict__ bpx,
    int* __restrict__ spill, int* __restrict__ spilln)
{
    const int tid = threadIdx.x;
    if (blockIdx.x == NBIN) {  // consts block, runs concurrently with binning
        float4 A, B, C, D;
        compute_consts(tid, u, v, theta, rel_sigma, rel_freq, gamma, psi,
                       amplitude, A, B, C, D);
        consts[tid] = A; consts[NG+tid] = B;
        consts[2*NG+tid] = C; consts[3*NG+tid] = D;
        return;
    }
    __shared__ int hist[NCELL];
    __shared__ int base[NCELL];
    #pragma unroll
    for (int i = 0; i < NCELL/256; ++i) hist[i*256 + tid] = 0;
    __syncthreads();

    uint32_t rec[PXB/256];
    float px[PXB/256], py[PXB/256];
    const int p0 = blockIdx.x * PXB;
    #pragma unroll
    for (int i = 0; i < PXB/256; ++i) {
        const int p = p0 + i*256 + tid;
        const float x = grid_x[p], y = grid_y[p];
        px[i] = x; py[i] = y;
        int ix = (int)(x * 32.0f); ix = min(max(ix, 0), 31);
        int iy = (int)(y * 32.0f); iy = min(max(iy, 0), 31);
        const int cell = iy*32 + ix;
        const int lr = atomicAdd(&hist[cell], 1);       // LDS atomic: cheap
        rec[i] = ((uint32_t)cell << 11) | (uint32_t)lr; // lr < 1024 fits 11b
    }
    __syncthreads();
    #pragma unroll
    for (int i = 0; i < NCELL/256; ++i) {
        const int c = i*256 + tid;
        const int h = hist[c];
        base[c] = (h > 0) ? atomicAdd(&counts[c], h) : 0;  // 1024 addresses
    }
    __syncthreads();
    #pragma unroll
    for (int i = 0; i < PXB/256; ++i) {
        const int p = p0 + i*256 + tid;
        const int cell = (int)(rec[i] >> 11);
        const int g = base[cell] + (int)(rec[i] & 0x7FFu);
        if (g < CAP) {
            bpx[cell*CAP + g] =
                make_float4(__int_as_float(p), px[i], py[i], 0.f);
        } else {
            const int t2 = atomicAdd(spilln, 1);
            if (t2 < SPILL_CAP) spill[t2] = p;
        }
    }
}

// ---------- kernel B: render. 1 block/cell x 256 thr. G1 gabors (hit whole
// ---------- cell) processed 2-at-a-time with packed v_pk_*_f32; G2 scalar.
__global__ __launch_bounds__(256) void gabor_render(
    const float4* __restrict__ consts, const int* __restrict__ counts,
    const float4* __restrict__ bpx,
    const int* __restrict__ spill, const int* __restrict__ spilln,
    const float* __restrict__ grid_x, const float* __restrict__ grid_y,
    float* __restrict__ out)
{
    // pair-packed SoA for G1 (2 gabors per slot)
    __shared__ float4 pkUV[NG/2];     // {u0,u1,v0,v1}
    __shared__ float4 pkROT[NG/2];    // {cr0,cr1,sr0,sr1}
    __shared__ float4 pkSG[NG/2];     // {is0,is1,ig0,ig1} (pre-negated*L2E)
    __shared__ float2 pkFQ[NG/2];     // {fq0,fq1}
    __shared__ float4 pkAMP[3][NG/2]; // per channel {ac0,ac1,as0,as1}
    // scalar AoS for G2
    __shared__ float4 c2A[NG], c2B[NG], c2C[NG], c2D[NG];
    __shared__ int s_wb1[4], s_wb2[4];

    const int cell = blockIdx.x;
    const int tid = threadIdx.x;
    const float cxc = ((cell & 31) + 0.5f) * 0.03125f;
    const float cyc = ((cell >> 5) + 0.5f) * 0.03125f;

    // --- inline cull + segmented compaction (G1 packed, G2 scalar) ---
    {
        const float4 A = consts[tid];
        const float4 B = consts[NG + tid];
        const float4 C = consts[2*NG + tid];
        const float4 D = consts[3*NG + tid];
        const float dx = cxc - A.x, dy = cyc - A.y;
        const float xrc = dx * A.z + dy * A.w;
        const float yrc = dy * A.z - dx * A.w;
        const float R = 0.0222f;            // cell half-diagonal + slack
        const float axr = fabsf(xrc), ayr = fabsf(yrc);
        const float xl = fmaxf(axr - R, 0.f), yl = fmaxf(ayr - R, 0.f);
        const float xh = axr + R,            yh = ayr + R;
        // B.x,B.y <= 0: e2 over the cell lies in [e2min, e2max]
        const float e2max = xl*xl*B.x + yl*yl*B.y;
        const float e2min = xh*xh*B.x + yh*yh*B.y;
        const bool nz = (C.x != 0.f) | (C.y != 0.f) | (C.z != 0.f) |
                        (D.x != 0.f) | (D.y != 0.f) | (D.z != 0.f);
        const bool act = (e2max > -20.0f) && nz;
        const bool g1  = act && (e2min > -20.0f);   // hits EVERY px in cell
        const bool g2  = act && !g1;                // edge gabor
        const unsigned long long m1 = __ballot(g1);
        const unsigned long long m2 = __ballot(g2);
        const int lane = tid & 63, w = tid >> 6;
        if (lane == 0) { s_wb1[w] = __popcll(m1); s_wb2[w] = __popcll(m2); }
        __syncthreads();
        int b1 = 0, b2 = 0;
        #pragma unroll
        for (int i = 0; i < 4; ++i) {
            b1 += (i < w) ? s_wb1[i] : 0;
            b2 += (i < w) ? s_wb2[i] : 0;
        }
        const unsigned long long lm = (1ull << lane) - 1ull;
        if (g1) {
            const int pos = b1 + __popcll(m1 & lm);
            const int q = pos >> 1, h = pos & 1;
            if (h == 0) {
                pkUV[q].x = A.x;  pkUV[q].z = A.y;
                pkROT[q].x = A.z; pkROT[q].z = A.w;
                pkSG[q].x = B.x;  pkSG[q].z = B.y;
                pkFQ[q].x = B.z;
                pkAMP[0][q].x = C.x; pkAMP[0][q].z = D.x;
                pkAMP[1][q].x = C.y; pkAMP[1][q].z = D.y;
                pkAMP[2][q].x = C.z; pkAMP[2][q].z = D.z;
            } else {
                pkUV[q].y = A.x;  pkUV[q].w = A.y;
                pkROT[q].y = A.z; pkROT[q].w = A.w;
                pkSG[q].y = B.x;  pkSG[q].w = B.y;
                pkFQ[q].y = B.z;
                pkAMP[0][q].y = C.x; pkAMP[0][q].w = D.x;
                pkAMP[1][q].y = C.y; pkAMP[1][q].w = D.y;
                pkAMP[2][q].y = C.z; pkAMP[2][q].w = D.z;
            }
        }
        if (g2) {
            const int pos = b2 + __popcll(m2 & lm);
            c2A[pos] = A; c2B[pos] = B; c2C[pos] = C; c2D[pos] = D;
        }
        __syncthreads();
    }
    const int n1 = s_wb1[0] + s_wb1[1] + s_wb1[2] + s_wb1[3];
    const int n2 = s_wb2[0] + s_wb2[1] + s_wb2[2] + s_wb2[3];
    // benign zero-amplitude pad so the packed loop can assume even count
    if (tid == 0 && (n1 & 1)) {
        const int q = n1 >> 1;
        pkUV[q].y = 0.f;  pkUV[q].w = 0.f;
        pkROT[q].y = 1.f; pkROT[q].w = 0.f;
        pkSG[q].y = 0.f;  pkSG[q].w = 0.f;   // e2=0 -> g=1, amp=0 -> contrib 0
        pkFQ[q].y = 0.f;
        pkAMP[0][q].y = 0.f; pkAMP[0][q].w = 0.f;
        pkAMP[1][q].y = 0.f; pkAMP[1][q].w = 0.f;
        pkAMP[2][q].y = 0.f; pkAMP[2][q].w = 0.f;
    }
    __syncthreads();
    const int n1p = (n1 + 1) >> 1;

    // --- pixel loop: 1 px/thread; G1 packed 2-gabors/iter, G2 scalar ---
    const float c1f = 0.15915494309189535f;
    const float c2f = (float)(INV2PI_D - (double)0.15915494309189535f);
    const v2f c1p = {c1f, c1f};
    const v2f c2p = {c2f, c2f};
    const int cnt = min(counts[cell], CAP);
    const int sb = cell * CAP;
    for (int i = tid; i < cnt; i += 256) {
        const float4 pxk = bpx[sb + i];
        const int   p  = __float_as_int(pxk.x);
        const float gx = pxk.y, gy = pxk.z;
        const v2f gxp = {gx, gx}, gyp = {gy, gy};
        v2f A0 = {0.f, 0.f}, A1 = {0.f, 0.f}, A2 = {0.f, 0.f};
        #pragma unroll 2
        for (int q = 0; q < n1p; ++q) {
            const float4 tuv = pkUV[q];
            const float4 trt = pkROT[q];
            const float4 tsg = pkSG[q];
            const float2 tfq = pkFQ[q];
            const v2f up  = {tuv.x, tuv.y}, vp  = {tuv.z, tuv.w};
            const v2f crp = {trt.x, trt.y}, srp = {trt.z, trt.w};
            const v2f isp = {tsg.x, tsg.y}, igp = {tsg.z, tsg.w};
            const v2f fqp = {tfq.x, tfq.y};
            const v2f dx = gxp - up;
            const v2f dy = gyp - vp;
            v2f xr, yr;
            {
                // phase-critical: np's separately-rounded mul/add, packed
                #pragma clang fp contract(off)
                xr = dx * crp + dy * srp;
                yr = dy * crp - dx * srp;
            }
            const v2f e2 = (xr * xr) * isp + (yr * yr) * igp;
            const v2f g = { __builtin_amdgcn_exp2f(e2.x),
                            __builtin_amdgcn_exp2f(e2.y) };
            v2f fx;
            {
                #pragma clang fp contract(off)
                fx = fqp * xr;               // phase-critical rounding
            }
            const v2f r1 = fx * c1p;
            const v2f nn = { __builtin_rintf(r1.x), __builtin_rintf(r1.y) };
            v2f t = __builtin_elementwise_fma(fx, c1p, -nn);
            t = __builtin_elementwise_fma(fx, c2p, t);
            const v2f s = { __builtin_amdgcn_sinf(t.x),
                            __builtin_amdgcn_sinf(t.y) };
            const v2f c = { __builtin_amdgcn_cosf(t.x),
                            __builtin_amdgcn_cosf(t.y) };
            const v2f gc = g * c, gs = g * s;
            const float4 am0 = pkAMP[0][q];
            const float4 am1 = pkAMP[1][q];
            const float4 am2 = pkAMP[2][q];
            const v2f ac0 = {am0.x, am0.y}, as0 = {am0.z, am0.w};
            const v2f ac1 = {am1.x, am1.y}, as1 = {am1.z, am1.w};
            const v2f ac2 = {am2.x, am2.y}, as2 = {am2.z, am2.w};
            A0 = __builtin_elementwise_fma(gc, ac0,
                 __builtin_elementwise_fma(-gs, as0, A0));
            A1 = __builtin_elementwise_fma(gc, ac1,
                 __builtin_elementwise_fma(-gs, as1, A1));
            A2 = __builtin_elementwise_fma(gc, ac2,
                 __builtin_elementwise_fma(-gs, as2, A2));
        }
        float a0 = A0.x + A0.y, a1 = A1.x + A1.y, a2 = A2.x + A2.y;
        // G2: edge gabors, scalar with skip branch
        for (int j = 0; j < n2; ++j) {
            const float4 k0 = c2A[j];
            const float4 k1 = c2B[j];
            const float dx = gx - k0.x;
            const float dy = gy - k0.y;
            float xr, yr;
            {
                #pragma clang fp contract(off)
                xr = dx * k0.z + dy * k0.w;
                yr = dy * k0.z - dx * k0.w;
            }
            const float e2 = fmaf(yr * yr, k1.y, xr * xr * k1.x);
            if (e2 > -20.0f) {
                const float g = __builtin_amdgcn_exp2f(e2);
                float fx;
                {
                    #pragma clang fp contract(off)
                    fx = k1.z * xr;
                }
                const float nn = __builtin_rintf(fx * c1f);
                float t = __builtin_fmaf(fx, c1f, -nn);
                t = __builtin_fmaf(fx, c2f, t);
                const float s = __builtin_amdgcn_sinf(t);
                const float c = __builtin_amdgcn_cosf(t);
                const float4 k2 = c2C[j];
                const float4 k3 = c2D[j];
                const float gc = g * c, gs = g * s;
                a0 = fmaf(gc, k2.x, fmaf(-gs, k3.x, a0));
                a1 = fmaf(gc, k2.y, fmaf(-gs, k3.y, a1));
                a2 = fmaf(gc, k2.z, fmaf(-gs, k3.z, a2));
            }
        }
        out[p]        = clampf(a0, -1.f, 1.f);
        out[HW + p]   = clampf(a1, -1.f, 1.f);
        out[2*HW + p] = clampf(a2, -1.f, 1.f);
    }

    // spill pixels (normally zero) handled by block 0 with full gabor list
    if (cell == 0) {
        const int sc = min(*spilln, SPILL_CAP);
        for (int i = tid; i < sc; i += 256) {
            const int p = spill[i];
            const float gx = grid_x[p], gy = grid_y[p];
            float a0 = 0.f, a1 = 0.f, a2 = 0.f;
            accum_list(consts, NG, gx, gy, a0, a1, a2);
            out[p]        = clampf(a0, -1.f, 1.f);
            out[HW + p]   = clampf(a1, -1.f, 1.f);
            out[2*HW + p] = clampf(a2, -1.f, 1.f);
        }
    }
}

// ---------- fallback paths (ws too small) ----------
__global__ __launch_bounds__(256) void gabor_consts_kernel(
    const float* __restrict__ u, const float* __restrict__ v,
    const float* __restrict__ theta, const float* __restrict__ rel_sigma,
    const float* __restrict__ rel_freq, const float* __restrict__ gamma,
    const float* __restrict__ psi, const float* __restrict__ amplitude,
    float4* __restrict__ ws)
{
    const int n = threadIdx.x;
    float4 A, B, C, D;
    compute_consts(n, u, v, theta, rel_sigma, rel_freq, gamma, psi, amplitude,
                   A, B, C, D);
    ws[n] = A; ws[NG + n] = B; ws[2*NG + n] = C; ws[3*NG + n] = D;
}

__global__ __launch_bounds__(256) void gabor_fwd_ws(
    const float4* __restrict__ ws,
    const float* __restrict__ grid_x, const float* __restrict__ grid_y,
    float* __restrict__ out)
{
    __shared__ float4 cs[4 * NG];
    const int tid = threadIdx.x;
    cs[tid]        = ws[tid];
    cs[tid + NG]   = ws[tid + NG];
    cs[tid + 2*NG] = ws[tid + 2*NG];
    cs[tid + 3*NG] = ws[tid + 3*NG];
    __syncthreads();
    const int p = blockIdx.x * 256 + tid;
    const float gx = grid_x[p], gy = grid_y[p];
    float a0 = 0.f, a1 = 0.f, a2 = 0.f;
    accum_list(cs, NG, gx, gy, a0, a1, a2);
    out[p]        = clampf(a0, -1.f, 1.f);
    out[HW + p]   = clampf(a1, -1.f, 1.f);
    out[2*HW + p] = clampf(a2, -1.f, 1.f);
}

__global__ __launch_bounds__(256) void gabor_fwd_fused(
    const float* __restrict__ grid_x, const float* __restrict__ grid_y,
    const float* __restrict__ u, const float* __restrict__ v,
    const float* __restrict__ theta, const float* __restrict__ rel_sigma,
    const float* __restrict__ rel_freq, const float* __restrict__ gamma,
    const float* __restrict__ psi, const float* __restrict__ amplitude,
    float* __restrict__ out)
{
    __shared__ float4 cs[4 * NG];
    const int tid = threadIdx.x;
    {
        float4 A, B, C, D;
        compute_consts(tid, u, v, theta, rel_sigma, rel_freq, gamma, psi,
                       amplitude, A, B, C, D);
        cs[tid] = A; cs[tid + NG] = B; cs[tid + 2*NG] = C; cs[tid + 3*NG] = D;
    }
    __syncthreads();
    const int p = blockIdx.x * 256 + tid;
    const float gx = grid_x[p], gy = grid_y[p];
    float a0 = 0.f, a1 = 0.f, a2 = 0.f;
    accum_list(cs, NG, gx, gy, a0, a1, a2);
    out[p]        = clampf(a0, -1.f, 1.f);
    out[HW + p]   = clampf(a1, -1.f, 1.f);
    out[2*HW + p] = clampf(a2, -1.f, 1.f);
}

extern "C" void kernel_launch(void* const* d_in, const int* in_sizes, int n_in,
                              void* d_out, int out_size, void* d_ws, size_t ws_size,
                              hipStream_t stream) {
    const float* grid_x    = (const float*)d_in[0];
    const float* grid_y    = (const float*)d_in[1];
    const float* u         = (const float*)d_in[2];
    const float* v         = (const float*)d_in[3];
    const float* theta     = (const float*)d_in[4];
    const float* rel_sigma = (const float*)d_in[5];
    const float* rel_freq  = (const float*)d_in[6];
    const float* gamma     = (const float*)d_in[7];
    const float* psi       = (const float*)d_in[8];
    const float* amplitude = (const float*)d_in[9];
    float* out = (float*)d_out;

    // ws layout (256B-aligned)
    const size_t OFF_CONSTS = 0;            // 16384
    const size_t OFF_COUNTS = 16384;        // 4096
    const size_t OFF_SPN    = 20480;        // 256
    const size_t OFF_SPILL  = 20736;        // 16384
    const size_t OFF_BPX    = 37120;        // 1024*384*16 = 6291456
    const size_t NEED       = 6328576;

    char* w = (char*)d_ws;

    if (ws_size >= NEED) {
        float4* consts = (float4*)(w + OFF_CONSTS);
        int*    counts = (int*)(w + OFF_COUNTS);
        int*    spn    = (int*)(w + OFF_SPN);
        int*    spill  = (int*)(w + OFF_SPILL);
        float4* bpx    = (float4*)(w + OFF_BPX);

        // zero counts + spilln (graph-capturable memset node)
        hipMemsetAsync(w + OFF_COUNTS, 0, 4096 + 256, stream);
        gabor_bin_consts<<<NBIN + 1, 256, 0, stream>>>(
            grid_x, grid_y, u, v, theta, rel_sigma, rel_freq, gamma,
            psi, amplitude, consts, counts, bpx, spill, spn);
        gabor_render<<<NCELL, 256, 0, stream>>>(
            consts, counts, bpx, spill, spn, grid_x, grid_y, out);
    } else if (ws_size >= 4u * NG * sizeof(float4)) {
        float4* ws = (float4*)d_ws;
        gabor_consts_kernel<<<1, NG, 0, stream>>>(
            u, v, theta, rel_sigma, rel_freq, gamma, psi, amplitude, ws);
        gabor_fwd_ws<<<HW / 256, 256, 0, stream>>>(ws, grid_x, grid_y, out);
    } else {
        gabor_fwd_fused<<<HW / 256, 256, 0, stream>>>(
            grid_x, grid_y, u, v, theta, rel_sigma, rel_freq, gamma,
            psi, amplitude, out);
    }
}

// Round 13
// 33.146 us; speedup vs baseline: 14.7965x; 1.0171x over previous
//
#include <hip/hip_runtime.h>
#include <stdint.h>

#define NG 256
#define HW (512*512)
#define NCELL 1024          // 32x32 cells
#define CAP 384             // bucket capacity per cell (Poisson(256), max ~330)
#define SPILL_CAP 4096
#define NBIN 256            // bin blocks
#define PXB (HW/NBIN)       // 1024 pixels per bin-block
#define TWO_PI_F 6.283185307179586f
#define L2E 1.4426950408889634f
#define INV2PI_D 0.15915494309189535
#define SKIP_THR (-16.0f)   // exp2(-16)=1.5e-5; skipped contrib << 0.0148 thr

typedef float v2f __attribute__((ext_vector_type(2)));

static __device__ __forceinline__ float clampf(float x, float lo, float hi) {
    return fminf(fmaxf(x, lo), hi);
}

// ---------- per-gabor constants (f64 -> correctly-rounded f32) ----------
static __device__ __forceinline__ void compute_consts(
    int n,
    const float* __restrict__ u, const float* __restrict__ v,
    const float* __restrict__ theta, const float* __restrict__ rel_sigma,
    const float* __restrict__ rel_freq, const float* __restrict__ gamma,
    const float* __restrict__ psi, const float* __restrict__ amplitude,
    float4& A, float4& B, float4& C, float4& D)
{
    const float uc = clampf(u[n], -1.f, 1.f);
    const float vc = clampf(v[n], -1.f, 1.f);
    const float th = clampf(theta[n], -2.f, 2.f) * TWO_PI_F;
    const float sg = clampf(rel_sigma[n], 1e-5f, 5.f);
    const float gm = clampf(gamma[n], 1e-5f, 5.f);
    const float cr = (float)::cos((double)th);
    const float sr = (float)::sin((double)th);
    const float i2s = 1.0f / (2.0f * sg * sg);
    const float i2g = 1.0f / (2.0f * gm * gm);
    const float E  = (float)::exp((double)rel_freq[n]);
    const float fq = TWO_PI_F / E;          // f32 division, mirrors np
    A = make_float4(uc, vc, cr, sr);
    B = make_float4(-(i2s * L2E), -(i2g * L2E), fq, 0.f);  // ready for exp2
    float ac[3], as[3];
    #pragma unroll
    for (int c = 0; c < 3; ++c) {
        const float ph = clampf(psi[n*3 + c], -1.f, 1.f) * TWO_PI_F;
        const float a  = clampf(amplitude[n*3 + c], 0.f, 1.f);
        ac[c] = a * (float)::cos((double)ph);
        as[c] = a * (float)::sin((double)ph);
    }
    C = make_float4(ac[0], ac[1], ac[2], 0.f);
    D = make_float4(as[0], as[1], as[2], 0.f);
}

// ---------- 1-pixel accumulate (spill + fallback paths) ----------
static __device__ __forceinline__ void accum_list(
    const float4* __restrict__ base, int ngab,
    float gx, float gy, float& a0, float& a1, float& a2)
{
    const float c1f = 0.15915494309189535f;
    const float c2f = (float)(INV2PI_D - (double)0.15915494309189535f);
    for (int j = 0; j < ngab; ++j) {
        const float4 k0 = base[j];
        const float4 k1 = base[NG + j];
        const float dx = gx - k0.x;
        const float dy = gy - k0.y;
        float xr, yr;
        {
            #pragma clang fp contract(off)
            xr = dx * k0.z + dy * k0.w;
            yr = dy * k0.z - dx * k0.w;
        }
        const float e2 = fmaf(yr * yr, k1.y, xr * xr * k1.x);
        if (e2 > SKIP_THR) {
            const float g = __builtin_amdgcn_exp2f(e2);
            float fx;
            {
                #pragma clang fp contract(off)
                fx = k1.z * xr;
            }
            const float nn = __builtin_rintf(fx * c1f);
            float t = __builtin_fmaf(fx, c1f, -nn);
            t = __builtin_fmaf(fx, c2f, t);
            const float s = __builtin_amdgcn_sinf(t);
            const float c = __builtin_amdgcn_cosf(t);
            const float4 k2 = base[2*NG + j];
            const float4 k3 = base[3*NG + j];
            const float gc = g * c, gs = g * s;
            a0 = fmaf(gc, k2.x, fmaf(-gs, k3.x, a0));
            a1 = fmaf(gc, k2.y, fmaf(-gs, k3.y, a1));
            a2 = fmaf(gc, k2.z, fmaf(-gs, k3.z, a2));
        }
    }
}

// ---------- kernel A: binning (blocks 0..255) + consts (block 256) ----------
__global__ __launch_bounds__(256) void gabor_bin_consts(
    const float* __restrict__ grid_x, const float* __restrict__ grid_y,
    const float* __restrict__ u, const float* __restrict__ v,
    const float* __restrict__ theta, const float* __restrict__ rel_sigma,
    const float* __restrict__ rel_freq, const float* __restrict__ gamma,
    const float* __restrict__ psi, const float* __restrict__ amplitude,
    float4* __restrict__ consts, int* __restrict__ counts,
    float4* __restrict__ bpx,
    int* __restrict__ spill, int* __restrict__ spilln)
{
    const int tid = threadIdx.x;
    if (blockIdx.x == NBIN) {  // consts block, runs concurrently with binning
        float4 A, B, C, D;
        compute_consts(tid, u, v, theta, rel_sigma, rel_freq, gamma, psi,
                       amplitude, A, B, C, D);
        consts[tid] = A; consts[NG+tid] = B;
        consts[2*NG+tid] = C; consts[3*NG+tid] = D;
        return;
    }
    __shared__ int hist[NCELL];
    __shared__ int base[NCELL];
    #pragma unroll
    for (int i = 0; i < NCELL/256; ++i) hist[i*256 + tid] = 0;
    __syncthreads();

    uint32_t rec[PXB/256];
    float px[PXB/256], py[PXB/256];
    const int p0 = blockIdx.x * PXB;
    #pragma unroll
    for (int i = 0; i < PXB/256; ++i) {
        const int p = p0 + i*256 + tid;
        const float x = grid_x[p], y = grid_y[p];
        px[i] = x; py[i] = y;
        int ix = (int)(x * 32.0f); ix = min(max(ix, 0), 31);
        int iy = (int)(y * 32.0f); iy = min(max(iy, 0), 31);
        const int cell = iy*32 + ix;
        const int lr = atomicAdd(&hist[cell], 1);       // LDS atomic: cheap
        rec[i] = ((uint32_t)cell << 11) | (uint32_t)lr; // lr < 1024 fits 11b
    }
    __syncthreads();
    #pragma unroll
    for (int i = 0; i < NCELL/256; ++i) {
        const int c = i*256 + tid;
        const int h = hist[c];
        base[c] = (h > 0) ? atomicAdd(&counts[c], h) : 0;  // 1024 addresses
    }
    __syncthreads();
    #pragma unroll
    for (int i = 0; i < PXB/256; ++i) {
        const int p = p0 + i*256 + tid;
        const int cell = (int)(rec[i] >> 11);
        const int g = base[cell] + (int)(rec[i] & 0x7FFu);
        if (g < CAP) {
            bpx[cell*CAP + g] =
                make_float4(__int_as_float(p), px[i], py[i], 0.f);
        } else {
            const int t2 = atomicAdd(spilln, 1);
            if (t2 < SPILL_CAP) spill[t2] = p;
        }
    }
}

// ---------- kernel B: render. 1 block/cell x 256 thr. G1 gabors (hit whole
// ---------- cell) processed 2-at-a-time with packed v_pk_*_f32; G2 scalar.
__global__ __launch_bounds__(256) void gabor_render(
    const float4* __restrict__ consts, const int* __restrict__ counts,
    const float4* __restrict__ bpx,
    const int* __restrict__ spill, const int* __restrict__ spilln,
    const float* __restrict__ grid_x, const float* __restrict__ grid_y,
    float* __restrict__ out)
{
    // pair-packed SoA for G1 (2 gabors per slot)
    __shared__ float4 pkUV[NG/2];     // {u0,u1,v0,v1}
    __shared__ float4 pkROT[NG/2];    // {cr0,cr1,sr0,sr1}
    __shared__ float4 pkSG[NG/2];     // {is0,is1,ig0,ig1} (pre-negated*L2E)
    __shared__ float2 pkFQ[NG/2];     // {fq0,fq1}
    __shared__ float4 pkAMP[3][NG/2]; // per channel {ac0,ac1,as0,as1}
    // scalar AoS for G2
    __shared__ float4 c2A[NG], c2B[NG], c2C[NG], c2D[NG];
    __shared__ int s_wb1[4], s_wb2[4];

    const int cell = blockIdx.x;
    const int tid = threadIdx.x;
    const float cxc = ((cell & 31) + 0.5f) * 0.03125f;
    const float cyc = ((cell >> 5) + 0.5f) * 0.03125f;

    // --- inline cull + segmented compaction (G1 packed, G2 scalar) ---
    {
        const float4 A = consts[tid];
        const float4 B = consts[NG + tid];
        const float4 C = consts[2*NG + tid];
        const float4 D = consts[3*NG + tid];
        const float dx = cxc - A.x, dy = cyc - A.y;
        const float xrc = dx * A.z + dy * A.w;
        const float yrc = dy * A.z - dx * A.w;
        const float R = 0.0222f;            // cell half-diagonal + slack
        const float axr = fabsf(xrc), ayr = fabsf(yrc);
        const float xl = fmaxf(axr - R, 0.f), yl = fmaxf(ayr - R, 0.f);
        const float xh = axr + R,            yh = ayr + R;
        // B.x,B.y <= 0: e2 over the cell lies in [e2min, e2max]
        const float e2max = xl*xl*B.x + yl*yl*B.y;
        const float e2min = xh*xh*B.x + yh*yh*B.y;
        const bool nz = (C.x != 0.f) | (C.y != 0.f) | (C.z != 0.f) |
                        (D.x != 0.f) | (D.y != 0.f) | (D.z != 0.f);
        const bool act = (e2max > SKIP_THR) && nz;
        const bool g1  = act && (e2min > SKIP_THR);  // hits EVERY px in cell
        const bool g2  = act && !g1;                 // edge gabor
        const unsigned long long m1 = __ballot(g1);
        const unsigned long long m2 = __ballot(g2);
        const int lane = tid & 63, w = tid >> 6;
        if (lane == 0) { s_wb1[w] = __popcll(m1); s_wb2[w] = __popcll(m2); }
        __syncthreads();
        int b1 = 0, b2 = 0;
        #pragma unroll
        for (int i = 0; i < 4; ++i) {
            b1 += (i < w) ? s_wb1[i] : 0;
            b2 += (i < w) ? s_wb2[i] : 0;
        }
        const unsigned long long lm = (1ull << lane) - 1ull;
        if (g1) {
            const int pos = b1 + __popcll(m1 & lm);
            const int q = pos >> 1, h = pos & 1;
            if (h == 0) {
                pkUV[q].x = A.x;  pkUV[q].z = A.y;
                pkROT[q].x = A.z; pkROT[q].z = A.w;
                pkSG[q].x = B.x;  pkSG[q].z = B.y;
                pkFQ[q].x = B.z;
                pkAMP[0][q].x = C.x; pkAMP[0][q].z = D.x;
                pkAMP[1][q].x = C.y; pkAMP[1][q].z = D.y;
                pkAMP[2][q].x = C.z; pkAMP[2][q].z = D.z;
            } else {
                pkUV[q].y = A.x;  pkUV[q].w = A.y;
                pkROT[q].y = A.z; pkROT[q].w = A.w;
                pkSG[q].y = B.x;  pkSG[q].w = B.y;
                pkFQ[q].y = B.z;
                pkAMP[0][q].y = C.x; pkAMP[0][q].w = D.x;
                pkAMP[1][q].y = C.y; pkAMP[1][q].w = D.y;
                pkAMP[2][q].y = C.z; pkAMP[2][q].w = D.z;
            }
        }
        if (g2) {
            const int pos = b2 + __popcll(m2 & lm);
            c2A[pos] = A; c2B[pos] = B; c2C[pos] = C; c2D[pos] = D;
        }
        __syncthreads();
    }
    const int n1 = s_wb1[0] + s_wb1[1] + s_wb1[2] + s_wb1[3];
    const int n2 = s_wb2[0] + s_wb2[1] + s_wb2[2] + s_wb2[3];
    // benign zero-amplitude pad so the packed loop can assume even count
    if (tid == 0 && (n1 & 1)) {
        const int q = n1 >> 1;
        pkUV[q].y = 0.f;  pkUV[q].w = 0.f;
        pkROT[q].y = 1.f; pkROT[q].w = 0.f;
        pkSG[q].y = 0.f;  pkSG[q].w = 0.f;   // e2=0 -> g=1, amp=0 -> contrib 0
        pkFQ[q].y = 0.f;
        pkAMP[0][q].y = 0.f; pkAMP[0][q].w = 0.f;
        pkAMP[1][q].y = 0.f; pkAMP[1][q].w = 0.f;
        pkAMP[2][q].y = 0.f; pkAMP[2][q].w = 0.f;
    }
    __syncthreads();
    const int n1p = (n1 + 1) >> 1;

    // --- pixel loop: 1 px/thread; G1 packed 2-gabors/iter, G2 scalar ---
    const float c1f = 0.15915494309189535f;
    const float c2f = (float)(INV2PI_D - (double)0.15915494309189535f);
    const v2f c1p = {c1f, c1f};
    const v2f c2p = {c2f, c2f};
    const int cnt = min(counts[cell], CAP);
    const int sb = cell * CAP;
    for (int i = tid; i < cnt; i += 256) {
        const float4 pxk = bpx[sb + i];
        const int   p  = __float_as_int(pxk.x);
        const float gx = pxk.y, gy = pxk.z;
        const v2f gxp = {gx, gx}, gyp = {gy, gy};
        v2f A0 = {0.f, 0.f}, A1 = {0.f, 0.f}, A2 = {0.f, 0.f};
        #pragma unroll 4
        for (int q = 0; q < n1p; ++q) {
            const float4 tuv = pkUV[q];
            const float4 trt = pkROT[q];
            const float4 tsg = pkSG[q];
            const float2 tfq = pkFQ[q];
            const v2f up  = {tuv.x, tuv.y}, vp  = {tuv.z, tuv.w};
            const v2f crp = {trt.x, trt.y}, srp = {trt.z, trt.w};
            const v2f isp = {tsg.x, tsg.y}, igp = {tsg.z, tsg.w};
            const v2f fqp = {tfq.x, tfq.y};
            const v2f dx = gxp - up;
            const v2f dy = gyp - vp;
            v2f xr, yr;
            {
                // phase-critical: np's separately-rounded mul/add, packed
                #pragma clang fp contract(off)
                xr = dx * crp + dy * srp;
                yr = dy * crp - dx * srp;
            }
            const v2f e2 = (xr * xr) * isp + (yr * yr) * igp;
            const v2f g = { __builtin_amdgcn_exp2f(e2.x),
                            __builtin_amdgcn_exp2f(e2.y) };
            v2f fx;
            {
                #pragma clang fp contract(off)
                fx = fqp * xr;               // phase-critical rounding
            }
            const v2f r1 = fx * c1p;
            const v2f nn = { __builtin_rintf(r1.x), __builtin_rintf(r1.y) };
            v2f t = __builtin_elementwise_fma(fx, c1p, -nn);
            t = __builtin_elementwise_fma(fx, c2p, t);
            const v2f s = { __builtin_amdgcn_sinf(t.x),
                            __builtin_amdgcn_sinf(t.y) };
            const v2f c = { __builtin_amdgcn_cosf(t.x),
                            __builtin_amdgcn_cosf(t.y) };
            const v2f gc = g * c, gs = g * s;
            const float4 am0 = pkAMP[0][q];
            const float4 am1 = pkAMP[1][q];
            const float4 am2 = pkAMP[2][q];
            const v2f ac0 = {am0.x, am0.y}, as0 = {am0.z, am0.w};
            const v2f ac1 = {am1.x, am1.y}, as1 = {am1.z, am1.w};
            const v2f ac2 = {am2.x, am2.y}, as2 = {am2.z, am2.w};
            A0 = __builtin_elementwise_fma(gc, ac0,
                 __builtin_elementwise_fma(-gs, as0, A0));
            A1 = __builtin_elementwise_fma(gc, ac1,
                 __builtin_elementwise_fma(-gs, as1, A1));
            A2 = __builtin_elementwise_fma(gc, ac2,
                 __builtin_elementwise_fma(-gs, as2, A2));
        }
        float a0 = A0.x + A0.y, a1 = A1.x + A1.y, a2 = A2.x + A2.y;
        // G2: edge gabors, scalar with skip branch
        for (int j = 0; j < n2; ++j) {
            const float4 k0 = c2A[j];
            const float4 k1 = c2B[j];
            const float dx = gx - k0.x;
            const float dy = gy - k0.y;
            float xr, yr;
            {
                #pragma clang fp contract(off)
                xr = dx * k0.z + dy * k0.w;
                yr = dy * k0.z - dx * k0.w;
            }
            const float e2 = fmaf(yr * yr, k1.y, xr * xr * k1.x);
            if (e2 > SKIP_THR) {
                const float g = __builtin_amdgcn_exp2f(e2);
                float fx;
                {
                    #pragma clang fp contract(off)
                    fx = k1.z * xr;
                }
                const float nn = __builtin_rintf(fx * c1f);
                float t = __builtin_fmaf(fx, c1f, -nn);
                t = __builtin_fmaf(fx, c2f, t);
                const float s = __builtin_amdgcn_sinf(t);
                const float c = __builtin_amdgcn_cosf(t);
                const float4 k2 = c2C[j];
                const float4 k3 = c2D[j];
                const float gc = g * c, gs = g * s;
                a0 = fmaf(gc, k2.x, fmaf(-gs, k3.x, a0));
                a1 = fmaf(gc, k2.y, fmaf(-gs, k3.y, a1));
                a2 = fmaf(gc, k2.z, fmaf(-gs, k3.z, a2));
            }
        }
        out[p]        = clampf(a0, -1.f, 1.f);
        out[HW + p]   = clampf(a1, -1.f, 1.f);
        out[2*HW + p] = clampf(a2, -1.f, 1.f);
    }

    // spill pixels (normally zero) handled by block 0 with full gabor list
    if (cell == 0) {
        const int sc = min(*spilln, SPILL_CAP);
        for (int i = tid; i < sc; i += 256) {
            const int p = spill[i];
            const float gx = grid_x[p], gy = grid_y[p];
            float a0 = 0.f, a1 = 0.f, a2 = 0.f;
            accum_list(consts, NG, gx, gy, a0, a1, a2);
            out[p]        = clampf(a0, -1.f, 1.f);
            out[HW + p]   = clampf(a1, -1.f, 1.f);
            out[2*HW + p] = clampf(a2, -1.f, 1.f);
        }
    }
}

// ---------- fallback paths (ws too small) ----------
__global__ __launch_bounds__(256) void gabor_consts_kernel(
    const float* __restrict__ u, const float* __restrict__ v,
    const float* __restrict__ theta, const float* __restrict__ rel_sigma,
    const float* __restrict__ rel_freq, const float* __restrict__ gamma,
    const float* __restrict__ psi, const float* __restrict__ amplitude,
    float4* __restrict__ ws)
{
    const int n = threadIdx.x;
    float4 A, B, C, D;
    compute_consts(n, u, v, theta, rel_sigma, rel_freq, gamma, psi, amplitude,
                   A, B, C, D);
    ws[n] = A; ws[NG + n] = B; ws[2*NG + n] = C; ws[3*NG + n] = D;
}

__global__ __launch_bounds__(256) void gabor_fwd_ws(
    const float4* __restrict__ ws,
    const float* __restrict__ grid_x, const float* __restrict__ grid_y,
    float* __restrict__ out)
{
    __shared__ float4 cs[4 * NG];
    const int tid = threadIdx.x;
    cs[tid]        = ws[tid];
    cs[tid + NG]   = ws[tid + NG];
    cs[tid + 2*NG] = ws[tid + 2*NG];
    cs[tid + 3*NG] = ws[tid + 3*NG];
    __syncthreads();
    const int p = blockIdx.x * 256 + tid;
    const float gx = grid_x[p], gy = grid_y[p];
    float a0 = 0.f, a1 = 0.f, a2 = 0.f;
    accum_list(cs, NG, gx, gy, a0, a1, a2);
    out[p]        = clampf(a0, -1.f, 1.f);
    out[HW + p]   = clampf(a1, -1.f, 1.f);
    out[2*HW + p] = clampf(a2, -1.f, 1.f);
}

__global__ __launch_bounds__(256) void gabor_fwd_fused(
    const float* __restrict__ grid_x, const float* __restrict__ grid_y,
    const float* __restrict__ u, const float* __restrict__ v,
    const float* __restrict__ theta, const float* __restrict__ rel_sigma,
    const float* __restrict__ rel_freq, const float* __restrict__ gamma,
    const float* __restrict__ psi, const float* __restrict__ amplitude,
    float* __restrict__ out)
{
    __shared__ float4 cs[4 * NG];
    const int tid = threadIdx.x;
    {
        float4 A, B, C, D;
        compute_consts(tid, u, v, theta, rel_sigma, rel_freq, gamma, psi,
                       amplitude, A, B, C, D);
        cs[tid] = A; cs[tid + NG] = B; cs[tid + 2*NG] = C; cs[tid + 3*NG] = D;
    }
    __syncthreads();
    const int p = blockIdx.x * 256 + tid;
    const float gx = grid_x[p], gy = grid_y[p];
    float a0 = 0.f, a1 = 0.f, a2 = 0.f;
    accum_list(cs, NG, gx, gy, a0, a1, a2);
    out[p]        = clampf(a0, -1.f, 1.f);
    out[HW + p]   = clampf(a1, -1.f, 1.f);
    out[2*HW + p] = clampf(a2, -1.f, 1.f);
}

extern "C" void kernel_launch(void* const* d_in, const int* in_sizes, int n_in,
                              void* d_out, int out_size, void* d_ws, size_t ws_size,
                              hipStream_t stream) {
    const float* grid_x    = (const float*)d_in[0];
    const float* grid_y    = (const float*)d_in[1];
    const float* u         = (const float*)d_in[2];
    const float* v         = (const float*)d_in[3];
    const float* theta     = (const float*)d_in[4];
    const float* rel_sigma = (const float*)d_in[5];
    const float* rel_freq  = (const float*)d_in[6];
    const float* gamma     = (const float*)d_in[7];
    const float* psi       = (const float*)d_in[8];
    const float* amplitude = (const float*)d_in[9];
    float* out = (float*)d_out;

    // ws layout (256B-aligned)
    const size_t OFF_CONSTS = 0;            // 16384
    const size_t OFF_COUNTS = 16384;        // 4096
    const size_t OFF_SPN    = 20480;        // 256
    const size_t OFF_SPILL  = 20736;        // 16384
    const size_t OFF_BPX    = 37120;        // 1024*384*16 = 6291456
    const size_t NEED       = 6328576;

    char* w = (char*)d_ws;

    if (ws_size >= NEED) {
        float4* consts = (float4*)(w + OFF_CONSTS);
        int*    counts = (int*)(w + OFF_COUNTS);
        int*    spn    = (int*)(w + OFF_SPN);
        int*    spill  = (int*)(w + OFF_SPILL);
        float4* bpx    = (float4*)(w + OFF_BPX);

        // zero counts + spilln (graph-capturable memset node)
        hipMemsetAsync(w + OFF_COUNTS, 0, 4096 + 256, stream);
        gabor_bin_consts<<<NBIN + 1, 256, 0, stream>>>(
            grid_x, grid_y, u, v, theta, rel_sigma, rel_freq, gamma,
            psi, amplitude, consts, counts, bpx, spill, spn);
        gabor_render<<<NCELL, 256, 0, stream>>>(
            consts, counts, bpx, spill, spn, grid_x, grid_y, out);
    } else if (ws_size >= 4u * NG * sizeof(float4)) {
        float4* ws = (float4*)d_ws;
        gabor_consts_kernel<<<1, NG, 0, stream>>>(
            u, v, theta, rel_sigma, rel_freq, gamma, psi, amplitude, ws);
        gabor_fwd_ws<<<HW / 256, 256, 0, stream>>>(ws, grid_x, grid_y, out);
    } else {
        gabor_fwd_fused<<<HW / 256, 256, 0, stream>>>(
            grid_x, grid_y, u, v, theta, rel_sigma, rel_freq, gamma,
            psi, amplitude, out);
    }
}